// Round 1
// baseline (1827.478 us; speedup 1.0000x reference)
//
#include <hip/hip_runtime.h>
#include <cstdint>
#include <cstddef>

#define H_   180
#define W_   360
#define HW_  64800
#define B_   2
#define NS_  128
#define NV_  64
#define HID_ 256
#define TW_  40
#define TPR_ 9   // 360 / 40 tiles per row

__device__ __forceinline__ float gelu_tanh(float x) {
  // JAX default gelu (approximate=True): 0.5x(1+tanh(sqrt(2/pi)(x+0.044715x^3)))
  float z = 0.7978845608028654f * (x + 0.044715f * x * x * x);
  float e = __expf(-2.0f * fabsf(z));
  float th = (1.0f - e) / (1.0f + e);
  th = (z >= 0.0f) ? th : -th;
  return 0.5f * x * (1.0f + th);
}

// ---------------------------------------------------------------------------
// Fold pointwise weights into conv center taps; transpose to o-contiguous.
// cw_s layout: [c][tap][o]   (NS*9*NS floats)
// cw_v layout: [c][tap][o/2][4] = (ws[o], ws[o+1], wr[o], wr[o+1])
// ---------------------------------------------------------------------------
__global__ void k_fuse_w(const float* __restrict__ cws_in, const float* __restrict__ pwss,
                         const float* __restrict__ cwv_in, const float* __restrict__ pvt,
                         float* __restrict__ cw_s, float* __restrict__ cw_v)
{
  const int idx = blockIdx.x * 256 + threadIdx.x;
  if (idx < NS_ * NS_) {
    const int o = idx / NS_, c = idx % NS_;
    #pragma unroll
    for (int tap = 0; tap < 9; ++tap) {
      float w = cws_in[(o * NS_ + c) * 9 + tap];
      if (tap == 4) w += pwss[o * NS_ + c];
      cw_s[(c * 9 + tap) * NS_ + o] = w;
    }
  }
  if (idx < NV_ * NV_) {
    const int o = idx / NV_, c = idx % NV_;
    const int og = o >> 1, oi = o & 1;
    #pragma unroll
    for (int tap = 0; tap < 9; ++tap) {
      float ws = cwv_in[((o * NV_ + c) * 2 + 0) * 9 + tap];
      float wr = cwv_in[((o * NV_ + c) * 2 + 1) * 9 + tap];
      if (tap == 4) {
        ws += pvt[(o * NV_ + c) * 2 + 0];
        wr += pvt[(o * NV_ + c) * 2 + 1];
      }
      cw_v[((c * 9 + tap) * 32 + og) * 4 + 0 + oi] = ws;
      cw_v[((c * 9 + tap) * 32 + og) * 4 + 2 + oi] = wr;
    }
  }
}

// ---------------------------------------------------------------------------
// Scalar conv (3x3, zero-pad H, circular W) + bias + gelu -> s_act (planar)
// block: one (b, y, 40-px tile). LDS holds 128ch x 3rows x 42px.
// thread: 4 out-channels x 5 px register tile.
// ---------------------------------------------------------------------------
__global__ __launch_bounds__(256) void k_conv_scalar(
    const float* __restrict__ x, const float* __restrict__ cw,
    const float* __restrict__ bias, float* __restrict__ s_act)
{
  __shared__ float tile[NS_][3][42];
  const int t = threadIdx.x;
  const int bid = blockIdx.x;
  const int b = bid / (H_ * TPR_);
  const int rem = bid % (H_ * TPR_);
  const int y = rem / TPR_;
  const int x0 = (rem % TPR_) * TW_;
  const float* xb = x + (size_t)b * NS_ * HW_;

  for (int idx = t; idx < NS_ * 3 * 42; idx += 256) {
    const int c = idx / 126;
    const int r2 = idx - c * 126;
    const int r = r2 / 42;
    const int j = r2 - r * 42;
    const int gy = y + r - 1;
    float v = 0.0f;
    if (gy >= 0 && gy < H_) {
      int gx = x0 - 1 + j;
      if (gx < 0) gx += W_;
      if (gx >= W_) gx -= W_;
      v = xb[(size_t)c * HW_ + gy * W_ + gx];
    }
    tile[c][r][j] = v;
  }
  __syncthreads();

  const int og = t >> 3;      // 0..31
  const int pg = t & 7;       // 0..7
  const int o = og * 4;
  const int xl = pg * 5;

  float acc[4][5];
  #pragma unroll
  for (int i = 0; i < 4; ++i)
    #pragma unroll
    for (int k = 0; k < 5; ++k) acc[i][k] = 0.0f;

  for (int c = 0; c < NS_; ++c) {
    #pragma unroll
    for (int r = 0; r < 3; ++r) {
      float in[7];
      #pragma unroll
      for (int j = 0; j < 7; ++j) in[j] = tile[c][r][xl + j];
      const float* wp = cw + (c * 9 + r * 3) * NS_ + o;
      #pragma unroll
      for (int dx = 0; dx < 3; ++dx) {
        const float4 w4 = *(const float4*)(wp + dx * NS_);
        #pragma unroll
        for (int k = 0; k < 5; ++k) {
          acc[0][k] = fmaf(w4.x, in[k + dx], acc[0][k]);
          acc[1][k] = fmaf(w4.y, in[k + dx], acc[1][k]);
          acc[2][k] = fmaf(w4.z, in[k + dx], acc[2][k]);
          acc[3][k] = fmaf(w4.w, in[k + dx], acc[3][k]);
        }
      }
    }
  }

  #pragma unroll
  for (int i = 0; i < 4; ++i) {
    const float bo = bias[o + i];
    float* op = s_act + (size_t)(b * NS_ + o + i) * HW_ + y * W_ + x0 + xl;
    #pragma unroll
    for (int k = 0; k < 5; ++k) op[k] = gelu_tanh(acc[i][k] + bo);
  }
}

// ---------------------------------------------------------------------------
// Fused per-pixel MLP + gate + residual + LayerNorm.
// block: 32 pixels, all channels. Lane map: pxg = t&3, px = pxg + 4*j (j<8).
// stage1: h = gelu(W1 sa + b1)   (4 ho x 8 px per thread)
// stage2: s2 = sa + W2 h + b2    (2 so x 8 px per thread)
// stage3: gate = sv s2 + svb     (1 go x 8 px per thread) -> gate buffer
// stage4: s2 += x_scalar; LN over 128 ch -> out_s
// ---------------------------------------------------------------------------
__global__ __launch_bounds__(256) void k_mlp_gate_ln(
    const float* __restrict__ s_act, const float* __restrict__ x,
    const float* __restrict__ w1, const float* __restrict__ b1,
    const float* __restrict__ w2, const float* __restrict__ b2,
    const float* __restrict__ svw, const float* __restrict__ svb,
    const float* __restrict__ gam, const float* __restrict__ bet,
    float* __restrict__ out_s, float* __restrict__ gate)
{
  __shared__ float smem[4224 + 8320 + 64];
  float* sa  = smem;                 // [32][132]
  float* hb  = smem + 4224;          // [32][260]
  float* s2  = hb;                   // alias (reused after stage 2 reads)
  float* mrs = smem + 4224 + 8320;   // [32][2]

  const int t = threadIdx.x;
  const int bid = blockIdx.x;
  const int b = bid / (HW_ / 32);
  const int p0 = (bid % (HW_ / 32)) * 32;

  for (int idx = t; idx < NS_ * 32; idx += 256) {
    const int c = idx >> 5, px = idx & 31;
    sa[px * 132 + c] = s_act[(size_t)(b * NS_ + c) * HW_ + p0 + px];
  }
  __syncthreads();

  const int pxg = t & 3;

  // ---- stage 1 ----
  {
    const int ho = (t >> 2) * 4;
    float hreg[4][8];
    #pragma unroll
    for (int i = 0; i < 4; ++i) {
      const float bb = b1[ho + i];
      #pragma unroll
      for (int j = 0; j < 8; ++j) hreg[i][j] = bb;
    }
    for (int c = 0; c < NS_; c += 4) {
      float4 wv[4];
      #pragma unroll
      for (int i = 0; i < 4; ++i) wv[i] = *(const float4*)(w1 + (ho + i) * NS_ + c);
      #pragma unroll
      for (int j = 0; j < 8; ++j) {
        const int px = pxg + j * 4;
        const float4 s4 = *(const float4*)(sa + px * 132 + c);
        #pragma unroll
        for (int i = 0; i < 4; ++i) {
          hreg[i][j] = fmaf(wv[i].x, s4.x, hreg[i][j]);
          hreg[i][j] = fmaf(wv[i].y, s4.y, hreg[i][j]);
          hreg[i][j] = fmaf(wv[i].z, s4.z, hreg[i][j]);
          hreg[i][j] = fmaf(wv[i].w, s4.w, hreg[i][j]);
        }
      }
    }
    #pragma unroll
    for (int j = 0; j < 8; ++j) {
      const int px = pxg + j * 4;
      #pragma unroll
      for (int i = 0; i < 4; ++i) hb[px * 260 + ho + i] = gelu_tanh(hreg[i][j]);
    }
  }
  __syncthreads();

  // ---- stage 2 ----
  const int so = (t >> 2) * 2;
  float a2[2][8];
  {
    #pragma unroll
    for (int i = 0; i < 2; ++i) {
      const float bb = b2[so + i];
      #pragma unroll
      for (int j = 0; j < 8; ++j) a2[i][j] = bb;
    }
    for (int c = 0; c < HID_; c += 4) {
      float4 wv0 = *(const float4*)(w2 + (so + 0) * HID_ + c);
      float4 wv1 = *(const float4*)(w2 + (so + 1) * HID_ + c);
      #pragma unroll
      for (int j = 0; j < 8; ++j) {
        const int px = pxg + j * 4;
        const float4 h4 = *(const float4*)(hb + px * 260 + c);
        a2[0][j] = fmaf(wv0.x, h4.x, a2[0][j]);
        a2[0][j] = fmaf(wv0.y, h4.y, a2[0][j]);
        a2[0][j] = fmaf(wv0.z, h4.z, a2[0][j]);
        a2[0][j] = fmaf(wv0.w, h4.w, a2[0][j]);
        a2[1][j] = fmaf(wv1.x, h4.x, a2[1][j]);
        a2[1][j] = fmaf(wv1.y, h4.y, a2[1][j]);
        a2[1][j] = fmaf(wv1.z, h4.z, a2[1][j]);
        a2[1][j] = fmaf(wv1.w, h4.w, a2[1][j]);
      }
    }
    #pragma unroll
    for (int j = 0; j < 8; ++j) {
      const int px = pxg + j * 4;
      a2[0][j] += sa[px * 132 + so + 0];
      a2[1][j] += sa[px * 132 + so + 1];
    }
  }
  __syncthreads();   // all reads of hb done before s2 alias write

  #pragma unroll
  for (int j = 0; j < 8; ++j) {
    const int px = pxg + j * 4;
    s2[px * 132 + so + 0] = a2[0][j];
    s2[px * 132 + so + 1] = a2[1][j];
  }
  __syncthreads();

  // ---- stage 3: gate ----
  {
    const int go = t >> 2;   // 0..63
    float ag[8];
    const float bb = svb[go];
    #pragma unroll
    for (int j = 0; j < 8; ++j) ag[j] = bb;
    for (int c = 0; c < NS_; c += 4) {
      const float4 wv = *(const float4*)(svw + go * NS_ + c);
      #pragma unroll
      for (int j = 0; j < 8; ++j) {
        const int px = pxg + j * 4;
        const float4 s4 = *(const float4*)(s2 + px * 132 + c);
        ag[j] = fmaf(wv.x, s4.x, ag[j]);
        ag[j] = fmaf(wv.y, s4.y, ag[j]);
        ag[j] = fmaf(wv.z, s4.z, ag[j]);
        ag[j] = fmaf(wv.w, s4.w, ag[j]);
      }
    }
    #pragma unroll
    for (int j = 0; j < 8; ++j)
      gate[(size_t)(b * NV_ + go) * HW_ + p0 + pxg + j * 4] = ag[j];
  }
  __syncthreads();  // stage-3 s2 reads done before stage-4 writes

  // ---- stage 4: residual + LN ----
  for (int idx = t; idx < NS_ * 32; idx += 256) {
    const int c = idx >> 5, px = idx & 31;
    s2[px * 132 + c] += x[(size_t)(b * NS_ + c) * HW_ + p0 + px];
  }
  __syncthreads();

  {
    const int px = t >> 3, k = t & 7;
    float sum = 0.0f, sq = 0.0f;
    #pragma unroll
    for (int c4 = 0; c4 < 16; c4 += 4) {
      const float4 v = *(const float4*)(s2 + px * 132 + k * 16 + c4);
      sum += v.x + v.y + v.z + v.w;
      sq = fmaf(v.x, v.x, sq);
      sq = fmaf(v.y, v.y, sq);
      sq = fmaf(v.z, v.z, sq);
      sq = fmaf(v.w, v.w, sq);
    }
    #pragma unroll
    for (int off = 1; off < 8; off <<= 1) {
      sum += __shfl_xor(sum, off);
      sq  += __shfl_xor(sq, off);
    }
    if (k == 0) {
      const float mean = sum * (1.0f / 128.0f);
      const float var = sq * (1.0f / 128.0f) - mean * mean;
      mrs[px * 2 + 0] = mean;
      mrs[px * 2 + 1] = rsqrtf(var + 1e-6f);
    }
  }
  __syncthreads();

  for (int idx = t; idx < NS_ * 32; idx += 256) {
    const int c = idx >> 5, px = idx & 31;
    const float v = (s2[px * 132 + c] - mrs[px * 2]) * mrs[px * 2 + 1] * gam[c] + bet[c];
    out_s[(size_t)(b * NS_ + c) * HW_ + p0 + px] = v;
  }
}

// ---------------------------------------------------------------------------
// Vector (complex) conv + gate residual + interleaved write to d_out.
// vu = conv(u,ws) - conv(v,wr); vv = conv(v,ws) + conv(u,wr)  (pointwise folded)
// out_u = u*(1+gate) + vu ; out_v = v*(1+gate) + vv
// thread: 2 out-channels x 5 px.
// ---------------------------------------------------------------------------
__global__ __launch_bounds__(256) void k_conv_vector(
    const float* __restrict__ xv, const float* __restrict__ cwv,
    const float* __restrict__ gate, float* __restrict__ out_v)
{
  __shared__ float ut[NV_][3][42];
  __shared__ float vt[NV_][3][42];
  const int t = threadIdx.x;
  const int bid = blockIdx.x;
  const int b = bid / (H_ * TPR_);
  const int rem = bid % (H_ * TPR_);
  const int y = rem / TPR_;
  const int x0 = (rem % TPR_) * TW_;
  const float* xvb = xv + (size_t)b * NV_ * HW_ * 2;

  for (int idx = t; idx < NV_ * 3 * 42; idx += 256) {
    const int c = idx / 126;
    const int r2 = idx - c * 126;
    const int r = r2 / 42;
    const int j = r2 - r * 42;
    const int gy = y + r - 1;
    float uu = 0.0f, vv = 0.0f;
    if (gy >= 0 && gy < H_) {
      int gx = x0 - 1 + j;
      if (gx < 0) gx += W_;
      if (gx >= W_) gx -= W_;
      const float2 p = *(const float2*)(xvb + ((size_t)c * HW_ + gy * W_ + gx) * 2);
      uu = p.x; vv = p.y;
    }
    ut[c][r][j] = uu;
    vt[c][r][j] = vv;
  }
  __syncthreads();

  const int og = t >> 3;      // 0..31
  const int pg = t & 7;
  const int o = og * 2;
  const int xl = pg * 5;

  float au[2][5], av[2][5];
  #pragma unroll
  for (int i = 0; i < 2; ++i)
    #pragma unroll
    for (int k = 0; k < 5; ++k) { au[i][k] = 0.0f; av[i][k] = 0.0f; }

  for (int c = 0; c < NV_; ++c) {
    #pragma unroll
    for (int r = 0; r < 3; ++r) {
      float uu[7], vv[7];
      #pragma unroll
      for (int j = 0; j < 7; ++j) { uu[j] = ut[c][r][xl + j]; vv[j] = vt[c][r][xl + j]; }
      const float4* wp = (const float4*)(cwv + ((c * 9 + r * 3) * 32 + og) * 4);
      #pragma unroll
      for (int dx = 0; dx < 3; ++dx) {
        const float4 w = wp[dx * 32];
        #pragma unroll
        for (int k = 0; k < 5; ++k) {
          au[0][k] = fmaf(w.x, uu[k + dx], au[0][k]);
          au[0][k] = fmaf(-w.z, vv[k + dx], au[0][k]);
          av[0][k] = fmaf(w.x, vv[k + dx], av[0][k]);
          av[0][k] = fmaf(w.z, uu[k + dx], av[0][k]);
          au[1][k] = fmaf(w.y, uu[k + dx], au[1][k]);
          au[1][k] = fmaf(-w.w, vv[k + dx], au[1][k]);
          av[1][k] = fmaf(w.y, vv[k + dx], av[1][k]);
          av[1][k] = fmaf(w.w, uu[k + dx], av[1][k]);
        }
      }
    }
  }

  #pragma unroll
  for (int i = 0; i < 2; ++i) {
    const int oc = o + i;
    #pragma unroll
    for (int k = 0; k < 5; ++k) {
      const size_t pix = (size_t)(b * NV_ + oc) * HW_ + y * W_ + x0 + xl + k;
      const float g = gate[pix];
      const float uc = ut[oc][1][1 + xl + k];
      const float vc = vt[oc][1][1 + xl + k];
      float2 r2;
      r2.x = au[i][k] + uc * (1.0f + g);
      r2.y = av[i][k] + vc * (1.0f + g);
      *(float2*)(out_v + pix * 2) = r2;
    }
  }
}

// ---------------------------------------------------------------------------
extern "C" void kernel_launch(void* const* d_in, const int* in_sizes, int n_in,
                              void* d_out, int out_size, void* d_ws, size_t ws_size,
                              hipStream_t stream) {
  const float* x_s      = (const float*)d_in[0];
  const float* x_v      = (const float*)d_in[1];
  const float* conv_ws_ = (const float*)d_in[2];
  const float* conv_bs_ = (const float*)d_in[3];
  const float* conv_wv_ = (const float*)d_in[4];
  const float* pw_ss    = (const float*)d_in[5];
  const float* pvt      = (const float*)d_in[6];
  const float* w1       = (const float*)d_in[7];
  const float* b1       = (const float*)d_in[8];
  const float* w2       = (const float*)d_in[9];
  const float* b2       = (const float*)d_in[10];
  const float* svw      = (const float*)d_in[11];
  const float* svb      = (const float*)d_in[12];
  const float* gam      = (const float*)d_in[13];
  const float* bet      = (const float*)d_in[14];

  float* ws    = (float*)d_ws;
  float* cw_s  = ws;                       // 147456 floats
  float* cw_v  = cw_s + 147456;            // 73728 floats
  float* s_act = cw_v + 73728;             // 16588800 floats
  float* gate  = s_act + 16588800;         // 8294400 floats

  float* out_s  = (float*)d_out;           // 16588800 floats
  float* out_vv = out_s + 16588800;        // 33177600 - 16588800 floats

  k_fuse_w<<<64, 256, 0, stream>>>(conv_ws_, pw_ss, conv_wv_, pvt, cw_s, cw_v);
  k_conv_scalar<<<B_ * H_ * TPR_, 256, 0, stream>>>(x_s, cw_s, conv_bs_, s_act);
  k_mlp_gate_ln<<<B_ * (HW_ / 32), 256, 0, stream>>>(s_act, x_s, w1, b1, w2, b2,
                                                     svw, svb, gam, bet, out_s, gate);
  k_conv_vector<<<B_ * H_ * TPR_, 256, 0, stream>>>(x_v, cw_v, gate, out_vv);
}

// Round 2
// 655.756 us; speedup vs baseline: 2.7868x; 2.7868x over previous
//
#include <hip/hip_runtime.h>
#include <cstdint>
#include <cstddef>

#define Hh 180
#define Ww 360
#define HW 64800

typedef __attribute__((ext_vector_type(8))) short bf16x8;
typedef __attribute__((ext_vector_type(4))) float f32x4;

__device__ __forceinline__ f32x4 MFMA(bf16x8 a, bf16x8 b, f32x4 c) {
  return __builtin_amdgcn_mfma_f32_16x16x32_bf16(a, b, c, 0, 0, 0);
}

__device__ __forceinline__ ushort f2bf(float f) {
  union { float f; uint32_t u; } x; x.f = f;
  uint32_t r = x.u + 0x7FFFu + ((x.u >> 16) & 1u);
  return (ushort)(r >> 16);
}
__device__ __forceinline__ float bf2f(ushort u) {
  union { uint32_t u; float f; } x; x.u = ((uint32_t)u) << 16;
  return x.f;
}
__device__ __forceinline__ float gelu_tanh(float x) {
  float z = 0.7978845608028654f * (x + 0.044715f * x * x * x);
  float e = __expf(-2.0f * fabsf(z));
  float th = (1.0f - e) / (1.0f + e);
  th = (z >= 0.0f) ? th : -th;
  return 0.5f * x * (1.0f + th);
}

// ---------------------------------------------------------------------------
// Pack all weights to bf16 fragment-ready layouts; fold pointwise into tap 4.
// wAs/wAv: [tap][cc][mt][lane][j]   (147456 each)
// wA1: [cc4][mt16][lane][j]  wA2: [cc8][mt8][lane][j]  wAg: [cc4][mt4][lane][j]
// ---------------------------------------------------------------------------
__global__ __launch_bounds__(256) void k_fuse_w(
    const float* __restrict__ cws, const float* __restrict__ pwss,
    const float* __restrict__ cwv, const float* __restrict__ pvt,
    const float* __restrict__ w1, const float* __restrict__ w2,
    const float* __restrict__ svw,
    ushort* __restrict__ wAs, ushort* __restrict__ wAv,
    ushort* __restrict__ wA1, ushort* __restrict__ wA2,
    ushort* __restrict__ wAg)
{
  const int idx = blockIdx.x * 256 + threadIdx.x;   // [0, 147456)
  const int j = idx & 7, l = (idx >> 3) & 63;
  const int lr = l & 15, h = l >> 4;
  {
    const int mt = (idx >> 9) & 7, tcc = idx >> 12;      // tcc 0..35
    const int tap = tcc >> 2, cc = tcc & 3;
    {
      const int o = mt * 16 + lr, c = cc * 32 + h * 8 + j;
      float w = cws[(o * 128 + c) * 9 + tap];
      if (tap == 4) w += pwss[o * 128 + c];
      wAs[idx] = f2bf(w);
    }
    {
      const int m = mt * 16 + lr;
      const int k = cc * 32 + h * 8 + j;
      const int c = k >> 1, part = k & 1, o = m & 63, half = m >> 6;
      float ws_ = cwv[((o * 64 + c) * 2 + 0) * 9 + tap];
      float wr_ = cwv[((o * 64 + c) * 2 + 1) * 9 + tap];
      if (tap == 4) {
        ws_ += pvt[(o * 64 + c) * 2 + 0];
        wr_ += pvt[(o * 64 + c) * 2 + 1];
      }
      const float w = (half == 0) ? (part == 0 ? ws_ : -wr_)
                                  : (part == 0 ? wr_ : ws_);
      wAv[idx] = f2bf(w);
    }
  }
  if (idx < 32768) {
    { const int mt = (idx >> 9) & 15, cc = idx >> 13;
      wA1[idx] = f2bf(w1[(mt * 16 + lr) * 128 + cc * 32 + h * 8 + j]); }
    { const int mt = (idx >> 9) & 7, cc = idx >> 12;
      wA2[idx] = f2bf(w2[(mt * 16 + lr) * 256 + cc * 32 + h * 8 + j]); }
  }
  if (idx < 8192) {
    const int mt = (idx >> 9) & 3, cc = idx >> 11;
    wAg[idx] = f2bf(svw[(mt * 16 + lr) * 128 + cc * 32 + h * 8 + j]);
  }
}

// ---------------------------------------------------------------------------
// Scalar conv via MFMA. Block: 128 oc x (4 rows x 32 cols). 4 waves (2m x 2n),
// wave = 4m x 4n 16x16 tiles, K = 9 taps x 4 cc-chunks of 32.
// LDS: input tile [6 rows][34 cols][128 ch] bf16, XOR-swizzled granules.
// ---------------------------------------------------------------------------
__global__ __launch_bounds__(256) void k_conv_s(
    const float* __restrict__ x, const ushort* __restrict__ wAs,
    const float* __restrict__ bias, ushort* __restrict__ sact)
{
  __shared__ __align__(16) ushort lds[6 * 34 * 128];   // 52224 B
  char* ldsb = (char*)lds;
  const int t = threadIdx.x;
  const int bid = blockIdx.x;
  const int b  = bid / 540;            // 45 row-tiles * 12 col-tiles
  const int r2 = bid % 540;
  const int rt = r2 / 12, ct = r2 % 12;
  const int y0 = rt * 4;
  int x0 = ct * 32; if (x0 > 328) x0 = 328;   // last tile overlaps (benign)
  const float* xb = x + (size_t)b * 128 * HW;

  for (int p = t; p < 64 * 204; p += 256) {
    const int c2 = p / 204;
    const int pos = p - c2 * 204;
    const int ir = pos / 34;
    const int ic = pos - ir * 34;
    const int gy = y0 - 1 + ir;
    int gx = x0 - 1 + ic;
    if (gx < 0) gx += 360; else if (gx >= 360) gx -= 360;
    uint32_t pk = 0;
    if (gy >= 0 && gy < 180) {
      const float f0 = xb[(size_t)(2 * c2) * HW + gy * 360 + gx];
      const float f1 = xb[(size_t)(2 * c2 + 1) * HW + gy * 360 + gx];
      pk = (uint32_t)f2bf(f0) | ((uint32_t)f2bf(f1) << 16);
    }
    const int addr = (pos << 8) + (((c2 >> 2) ^ (ic & 15)) << 4) + ((c2 & 3) << 2);
    *(uint32_t*)(ldsb + addr) = pk;
  }
  __syncthreads();

  const int w = t >> 6, lane = t & 63;
  const int wm = w >> 1, wn = w & 1;
  const int lr = lane & 15, h = lane >> 4;
  const int h16 = h << 4;

  f32x4 acc[4][4];
  #pragma unroll
  for (int i = 0; i < 4; ++i)
    #pragma unroll
    for (int n = 0; n < 4; ++n) acc[i][n] = f32x4{0.f, 0.f, 0.f, 0.f};

  for (int tap = 0; tap < 9; ++tap) {
    const int dy = tap / 3, dx = tap - dy * 3;
    int rb[4], xr[4];
    #pragma unroll
    for (int in = 0; in < 4; ++in) {
      const int nt = wn * 4 + in;
      const int ic = (nt & 1) * 16 + lr + dx;
      rb[in] = (((nt >> 1) + dy) * 34 + ic) << 8;
      xr[in] = (ic & 15) << 4;
    }
    #pragma unroll
    for (int cc = 0; cc < 4; ++cc) {
      bf16x8 af[4];
      const ushort* ap = wAs + (size_t)(((tap * 4 + cc) * 8 + wm * 4) * 64 + lane) * 8;
      #pragma unroll
      for (int im = 0; im < 4; ++im)
        af[im] = *(const bf16x8*)(ap + im * 512);
      const int gh = (cc << 6) + h16;
      #pragma unroll
      for (int in = 0; in < 4; ++in) {
        const bf16x8 bfr = *(const bf16x8*)(ldsb + rb[in] + (gh ^ xr[in]));
        #pragma unroll
        for (int im = 0; im < 4; ++im)
          acc[im][in] = MFMA(af[im], bfr, acc[im][in]);
      }
    }
  }

  #pragma unroll
  for (int im = 0; im < 4; ++im) {
    #pragma unroll
    for (int r = 0; r < 4; ++r) {
      const int o = (wm * 4 + im) * 16 + h * 4 + r;
      const float bo = bias[o];
      ushort* op = sact + (size_t)(b * 128 + o) * HW;
      #pragma unroll
      for (int in = 0; in < 4; ++in) {
        const int nt = wn * 4 + in;
        const int gy = y0 + (nt >> 1);
        const int gx = x0 + (nt & 1) * 16 + lr;
        op[gy * 360 + gx] = f2bf(gelu_tanh(acc[im][in][r] + bo));
      }
    }
  }
}

// ---------------------------------------------------------------------------
// Vector (complex) conv via MFMA + gate residual. Same geometry; LDS channel
// dim = 64 complex interleaved (u,v) = 128 bf16. A rows: [0,64)=vu, [64,128)=vv.
// Wave wm owns m-tiles {2wm, 2wm+1, 2wm+4, 2wm+5} so (vu,vv) pair per lane.
// ---------------------------------------------------------------------------
__global__ __launch_bounds__(256) void k_conv_v(
    const float* __restrict__ xv, const ushort* __restrict__ wAv,
    const float* __restrict__ gate, float* __restrict__ outv)
{
  __shared__ __align__(16) ushort lds[6 * 34 * 128];
  char* ldsb = (char*)lds;
  const int t = threadIdx.x;
  const int bid = blockIdx.x;
  const int b  = bid / 540;
  const int r2 = bid % 540;
  const int rt = r2 / 12, ct = r2 % 12;
  const int y0 = rt * 4;
  int x0 = ct * 32; if (x0 > 328) x0 = 328;
  const float* xvb = xv + (size_t)b * 64 * HW * 2;

  for (int p = t; p < 64 * 204; p += 256) {
    const int c = p / 204;
    const int pos = p - c * 204;
    const int ir = pos / 34;
    const int ic = pos - ir * 34;
    const int gy = y0 - 1 + ir;
    int gx = x0 - 1 + ic;
    if (gx < 0) gx += 360; else if (gx >= 360) gx -= 360;
    uint32_t pk = 0;
    if (gy >= 0 && gy < 180) {
      const float2 f = *(const float2*)(xvb + ((size_t)c * HW + gy * 360 + gx) * 2);
      pk = (uint32_t)f2bf(f.x) | ((uint32_t)f2bf(f.y) << 16);
    }
    const int addr = (pos << 8) + (((c >> 2) ^ (ic & 15)) << 4) + ((c & 3) << 2);
    *(uint32_t*)(ldsb + addr) = pk;
  }
  __syncthreads();

  const int w = t >> 6, lane = t & 63;
  const int wm = w >> 1, wn = w & 1;
  const int lr = lane & 15, h = lane >> 4;
  const int h16 = h << 4;
  int mtab[4];
  #pragma unroll
  for (int im = 0; im < 4; ++im) mtab[im] = wm * 2 + (im & 1) + (im >> 1) * 4;

  f32x4 acc[4][4];
  #pragma unroll
  for (int i = 0; i < 4; ++i)
    #pragma unroll
    for (int n = 0; n < 4; ++n) acc[i][n] = f32x4{0.f, 0.f, 0.f, 0.f};

  for (int tap = 0; tap < 9; ++tap) {
    const int dy = tap / 3, dx = tap - dy * 3;
    int rb[4], xr[4];
    #pragma unroll
    for (int in = 0; in < 4; ++in) {
      const int nt = wn * 4 + in;
      const int ic = (nt & 1) * 16 + lr + dx;
      rb[in] = (((nt >> 1) + dy) * 34 + ic) << 8;
      xr[in] = (ic & 15) << 4;
    }
    #pragma unroll
    for (int cc = 0; cc < 4; ++cc) {
      bf16x8 af[4];
      #pragma unroll
      for (int im = 0; im < 4; ++im)
        af[im] = *(const bf16x8*)(wAv + (size_t)(((tap * 4 + cc) * 8 + mtab[im]) * 64 + lane) * 8);
      const int gh = (cc << 6) + h16;
      #pragma unroll
      for (int in = 0; in < 4; ++in) {
        const bf16x8 bfr = *(const bf16x8*)(ldsb + rb[in] + (gh ^ xr[in]));
        #pragma unroll
        for (int im = 0; im < 4; ++im)
          acc[im][in] = MFMA(af[im], bfr, acc[im][in]);
      }
    }
  }

  #pragma unroll
  for (int i = 0; i < 2; ++i) {
    #pragma unroll
    for (int r = 0; r < 4; ++r) {
      const int o = (wm * 2 + i) * 16 + h * 4 + r;
      #pragma unroll
      for (int in = 0; in < 4; ++in) {
        const int nt = wn * 4 + in;
        const int gy = y0 + (nt >> 1);
        const int gx = x0 + (nt & 1) * 16 + lr;
        const size_t pix = (size_t)(b * 64 + o) * HW + gy * 360 + gx;
        const float g1 = 1.0f + gate[pix];
        const float2 c0 = *(const float2*)(xv + pix * 2);
        float2 rr;
        rr.x = acc[i][in][r] + c0.x * g1;
        rr.y = acc[i + 2][in][r] + c0.y * g1;
        *(float2*)(outv + pix * 2) = rr;
      }
    }
  }
}

// ---------------------------------------------------------------------------
// Fused MLP + gate + residual + LayerNorm via MFMA. Block = 80 px strip.
// sa: [80][128] bf16 (later s2 bf16); hb: [80][256] bf16 (later s_final f32).
// ---------------------------------------------------------------------------
__global__ __launch_bounds__(256) void k_mlp(
    const ushort* __restrict__ sact, const float* __restrict__ x,
    const ushort* __restrict__ wA1, const float* __restrict__ b1,
    const ushort* __restrict__ wA2, const float* __restrict__ b2,
    const ushort* __restrict__ wAg, const float* __restrict__ svb,
    const float* __restrict__ gam, const float* __restrict__ bet,
    float* __restrict__ outs, float* __restrict__ gate)
{
  __shared__ __align__(16) char ldsb[80 * 256 + 80 * 512 + 80 * 8];
  char* sab = ldsb;
  char* hbb = ldsb + 20480;
  float* mrs = (float*)(ldsb + 61440);

  const int t = threadIdx.x;
  const int bid = blockIdx.x;
  const int b = bid / 810, pb = bid % 810;
  const int p0 = pb * 80;
  const int w = t >> 6, lane = t & 63, lr = lane & 15, h = lane >> 4;
  const int h16 = h << 4, lr16 = lr << 4;

  for (int p = t; p < 64 * 80; p += 256) {
    const int c2 = p / 80, px = p - c2 * 80;
    const ushort u0 = sact[(size_t)(b * 128 + 2 * c2) * HW + p0 + px];
    const ushort u1 = sact[(size_t)(b * 128 + 2 * c2 + 1) * HW + p0 + px];
    const uint32_t pk = (uint32_t)u0 | ((uint32_t)u1 << 16);
    const int addr = (px << 8) + (((c2 >> 2) ^ (px & 15)) << 4) + ((c2 & 3) << 2);
    *(uint32_t*)(sab + addr) = pk;
  }
  __syncthreads();

  // stage 1: h = gelu(W1 sa + b1); wave w -> h-channels [w*64, w*64+64)
  {
    f32x4 a1[4][5];
    #pragma unroll
    for (int i = 0; i < 4; ++i)
      #pragma unroll
      for (int n = 0; n < 5; ++n) a1[i][n] = f32x4{0.f, 0.f, 0.f, 0.f};
    #pragma unroll
    for (int cc = 0; cc < 4; ++cc) {
      bf16x8 af[4];
      const ushort* ap = wA1 + (size_t)((cc * 16 + w * 4) * 64 + lane) * 8;
      #pragma unroll
      for (int im = 0; im < 4; ++im) af[im] = *(const bf16x8*)(ap + im * 512);
      const int gh = (cc << 6) + h16;
      #pragma unroll
      for (int in = 0; in < 5; ++in) {
        const bf16x8 bfr = *(const bf16x8*)(sab + ((in * 16 + lr) << 8) + (gh ^ lr16));
        #pragma unroll
        for (int im = 0; im < 4; ++im) a1[im][in] = MFMA(af[im], bfr, a1[im][in]);
      }
    }
    #pragma unroll
    for (int im = 0; im < 4; ++im) {
      const int C0 = (w * 4 + im) * 16 + h * 4;
      #pragma unroll
      for (int in = 0; in < 5; ++in) {
        const int px = in * 16 + lr;
        const float g0 = gelu_tanh(a1[im][in][0] + b1[C0 + 0]);
        const float g1 = gelu_tanh(a1[im][in][1] + b1[C0 + 1]);
        const float g2 = gelu_tanh(a1[im][in][2] + b1[C0 + 2]);
        const float g3 = gelu_tanh(a1[im][in][3] + b1[C0 + 3]);
        const int ad = (px << 9) + ((((C0 >> 3) ^ (px & 15))) << 4) + ((C0 & 7) << 1);
        *(uint32_t*)(hbb + ad)     = (uint32_t)f2bf(g0) | ((uint32_t)f2bf(g1) << 16);
        *(uint32_t*)(hbb + ad + 4) = (uint32_t)f2bf(g2) | ((uint32_t)f2bf(g3) << 16);
      }
    }
  }
  __syncthreads();

  // stage 2: s2 = sa + W2 h + b2 ; wave w -> channels [w*32, w*32+32)
  f32x4 a2[2][5];
  #pragma unroll
  for (int i = 0; i < 2; ++i)
    #pragma unroll
    for (int n = 0; n < 5; ++n) a2[i][n] = f32x4{0.f, 0.f, 0.f, 0.f};
  #pragma unroll
  for (int cc = 0; cc < 8; ++cc) {
    const ushort* ap = wA2 + (size_t)((cc * 8 + w * 2) * 64 + lane) * 8;
    const bf16x8 af0 = *(const bf16x8*)(ap);
    const bf16x8 af1 = *(const bf16x8*)(ap + 512);
    const int gh = (cc << 6) + h16;
    #pragma unroll
    for (int in = 0; in < 5; ++in) {
      const bf16x8 bfr = *(const bf16x8*)(hbb + ((in * 16 + lr) << 9) + (gh ^ lr16));
      a2[0][in] = MFMA(af0, bfr, a2[0][in]);
      a2[1][in] = MFMA(af1, bfr, a2[1][in]);
    }
  }
  #pragma unroll
  for (int im = 0; im < 2; ++im) {
    const int C0 = (w * 2 + im) * 16 + h * 4;
    #pragma unroll
    for (int r = 0; r < 4; ++r) {
      const int c = C0 + r;
      const float bb = b2[c];
      #pragma unroll
      for (int in = 0; in < 5; ++in) {
        const int px = in * 16 + lr;
        const int ad = (px << 8) + ((((c >> 3) ^ (px & 15))) << 4) + ((c & 7) << 1);
        a2[im][in][r] += bb + bf2f(*(const ushort*)(sab + ad));
      }
    }
  }
  __syncthreads();   // all sa/hb reads done

  #pragma unroll
  for (int im = 0; im < 2; ++im) {
    const int C0 = (w * 2 + im) * 16 + h * 4;
    const int gsf = (w * 2 + im) * 4 + h;
    #pragma unroll
    for (int in = 0; in < 5; ++in) {
      const int px = in * 16 + lr;
      const int ad = (px << 8) + ((((C0 >> 3) ^ (px & 15))) << 4) + ((C0 & 7) << 1);
      *(uint32_t*)(sab + ad)     = (uint32_t)f2bf(a2[im][in][0]) | ((uint32_t)f2bf(a2[im][in][1]) << 16);
      *(uint32_t*)(sab + ad + 4) = (uint32_t)f2bf(a2[im][in][2]) | ((uint32_t)f2bf(a2[im][in][3]) << 16);
      const int ad2 = (px << 9) + ((gsf ^ (px & 15)) << 4);
      *(f32x4*)(hbb + ad2) = a2[im][in];
    }
  }
  __syncthreads();

  // s_final = s2 + x  (into fp32 buffer)
  for (int i = t; i < 128 * 80; i += 256) {
    const int c = i / 80, px = i - c * 80;
    const float xv_ = x[(size_t)(b * 128 + c) * HW + p0 + px];
    const int ad = (px << 9) + ((((c >> 2) ^ (px & 15))) << 4) + ((c & 3) << 2);
    *(float*)(hbb + ad) += xv_;
  }
  __syncthreads();

  // gate = svw * s2 + svb ; wave w -> gate channels [w*16, w*16+16)
  {
    f32x4 ag[5];
    #pragma unroll
    for (int n = 0; n < 5; ++n) ag[n] = f32x4{0.f, 0.f, 0.f, 0.f};
    #pragma unroll
    for (int cc = 0; cc < 4; ++cc) {
      const bf16x8 af = *(const bf16x8*)(wAg + (size_t)((cc * 4 + w) * 64 + lane) * 8);
      const int gh = (cc << 6) + h16;
      #pragma unroll
      for (int in = 0; in < 5; ++in) {
        const bf16x8 bfr = *(const bf16x8*)(sab + ((in * 16 + lr) << 8) + (gh ^ lr16));
        ag[in] = MFMA(af, bfr, ag[in]);
      }
    }
    #pragma unroll
    for (int r = 0; r < 4; ++r) {
      const int o = w * 16 + h * 4 + r;
      const float bb = svb[o];
      #pragma unroll
      for (int in = 0; in < 5; ++in)
        gate[(size_t)(b * 64 + o) * HW + p0 + in * 16 + lr] = ag[in][r] + bb;
    }
  }

  // LN stats
  if (t < 160) {
    const int px = t >> 1, half = t & 1;
    float sum = 0.f, sq = 0.f;
    #pragma unroll
    for (int i = 0; i < 16; ++i) {
      const int g = half * 16 + i;
      const f32x4 v = *(const f32x4*)(hbb + (px << 9) + ((g ^ (px & 15)) << 4));
      sum += v[0] + v[1] + v[2] + v[3];
      sq = fmaf(v[0], v[0], sq); sq = fmaf(v[1], v[1], sq);
      sq = fmaf(v[2], v[2], sq); sq = fmaf(v[3], v[3], sq);
    }
    sum += __shfl_xor(sum, 1);
    sq  += __shfl_xor(sq, 1);
    if (half == 0) {
      const float mean = sum * (1.0f / 128.0f);
      const float var  = sq * (1.0f / 128.0f) - mean * mean;
      mrs[px * 2 + 0] = mean;
      mrs[px * 2 + 1] = rsqrtf(var + 1e-6f);
    }
  }
  __syncthreads();

  for (int i = t; i < 128 * 80; i += 256) {
    const int c = i / 80, px = i - c * 80;
    const int ad = (px << 9) + ((((c >> 2) ^ (px & 15))) << 4) + ((c & 3) << 2);
    const float v = *(const float*)(hbb + ad);
    outs[(size_t)(b * 128 + c) * HW + p0 + px] =
        (v - mrs[px * 2]) * mrs[px * 2 + 1] * gam[c] + bet[c];
  }
}

// ---------------------------------------------------------------------------
extern "C" void kernel_launch(void* const* d_in, const int* in_sizes, int n_in,
                              void* d_out, int out_size, void* d_ws, size_t ws_size,
                              hipStream_t stream) {
  const float* x_s  = (const float*)d_in[0];
  const float* x_v  = (const float*)d_in[1];
  const float* cws  = (const float*)d_in[2];
  const float* cbs  = (const float*)d_in[3];
  const float* cwv  = (const float*)d_in[4];
  const float* pwss = (const float*)d_in[5];
  const float* pvt  = (const float*)d_in[6];
  const float* w1   = (const float*)d_in[7];
  const float* b1   = (const float*)d_in[8];
  const float* w2   = (const float*)d_in[9];
  const float* b2   = (const float*)d_in[10];
  const float* svw  = (const float*)d_in[11];
  const float* svb  = (const float*)d_in[12];
  const float* gam  = (const float*)d_in[13];
  const float* bet  = (const float*)d_in[14];

  char* wsb = (char*)d_ws;
  ushort* wAs  = (ushort*)(wsb);
  ushort* wAv  = (ushort*)(wsb + 294912);
  ushort* wA1  = (ushort*)(wsb + 589824);
  ushort* wA2  = (ushort*)(wsb + 655360);
  ushort* wAg  = (ushort*)(wsb + 720896);
  ushort* sact = (ushort*)(wsb + 737280);
  float*  gate = (float*)(wsb + 737280 + 66355200);

  float* outs = (float*)d_out;
  float* outv = outs + 16588800;

  k_fuse_w<<<576, 256, 0, stream>>>(cws, pwss, cwv, pvt, w1, w2, svw,
                                    wAs, wAv, wA1, wA2, wAg);
  k_conv_s<<<1080, 256, 0, stream>>>(x_s, wAs, cbs, sact);
  k_mlp<<<1620, 256, 0, stream>>>(sact, x_s, wA1, b1, wA2, b2, wAg, svb,
                                  gam, bet, outs, gate);
  k_conv_v<<<1080, 256, 0, stream>>>(x_v, wAv, gate, outv);
}

// Round 3
// 494.023 us; speedup vs baseline: 3.6992x; 1.3274x over previous
//
#include <hip/hip_runtime.h>
#include <cstdint>
#include <cstddef>

#define HW 64800

typedef __attribute__((ext_vector_type(8))) short bf16x8;
typedef __attribute__((ext_vector_type(4))) float f32x4;

__device__ __forceinline__ f32x4 MFMA(bf16x8 a, bf16x8 b, f32x4 c) {
  return __builtin_amdgcn_mfma_f32_16x16x32_bf16(a, b, c, 0, 0, 0);
}

__device__ __forceinline__ ushort f2bf(float f) {
  union { float f; uint32_t u; } x; x.f = f;
  uint32_t r = x.u + 0x7FFFu + ((x.u >> 16) & 1u);
  return (ushort)(r >> 16);
}
__device__ __forceinline__ float bf2f(ushort u) {
  union { uint32_t u; float f; } x; x.u = ((uint32_t)u) << 16;
  return x.f;
}
__device__ __forceinline__ float gelu_tanh(float x) {
  float z = 0.7978845608028654f * (x + 0.044715f * x * x * x);
  float e = __expf(-2.0f * fabsf(z));
  float th = (1.0f - e) / (1.0f + e);
  th = (z >= 0.0f) ? th : -th;
  return 0.5f * x * (1.0f + th);
}

// async 16B global->LDS (DMA, no VGPR round-trip). LDS dest: uniform base + lane*16.
__device__ __forceinline__ void gload16(const void* g, void* l) {
  __builtin_amdgcn_global_load_lds((__attribute__((address_space(1))) const void*)g,
                                   (__attribute__((address_space(3))) void*)l, 16, 0, 0);
}

// ---------------------------------------------------------------------------
// Pack weights to bf16 fragment-ready layouts; fold pointwise into tap 4.
// ---------------------------------------------------------------------------
__global__ __launch_bounds__(256) void k_fuse_w(
    const float* __restrict__ cws, const float* __restrict__ pwss,
    const float* __restrict__ cwv, const float* __restrict__ pvt,
    const float* __restrict__ w1, const float* __restrict__ w2,
    const float* __restrict__ svw,
    ushort* __restrict__ wAs, ushort* __restrict__ wAv,
    ushort* __restrict__ wA1, ushort* __restrict__ wA2,
    ushort* __restrict__ wAg)
{
  const int idx = blockIdx.x * 256 + threadIdx.x;   // [0, 147456)
  const int j = idx & 7, l = (idx >> 3) & 63;
  const int lr = l & 15, h = l >> 4;
  {
    const int mt = (idx >> 9) & 7, tcc = idx >> 12;      // tcc 0..35
    const int tap = tcc >> 2, cc = tcc & 3;
    {
      const int o = mt * 16 + lr, c = cc * 32 + h * 8 + j;
      float w = cws[(o * 128 + c) * 9 + tap];
      if (tap == 4) w += pwss[o * 128 + c];
      wAs[idx] = f2bf(w);
    }
    {
      const int m = mt * 16 + lr;
      const int k = cc * 32 + h * 8 + j;
      const int c = k >> 1, part = k & 1, o = m & 63, half = m >> 6;
      float ws_ = cwv[((o * 64 + c) * 2 + 0) * 9 + tap];
      float wr_ = cwv[((o * 64 + c) * 2 + 1) * 9 + tap];
      if (tap == 4) {
        ws_ += pvt[(o * 64 + c) * 2 + 0];
        wr_ += pvt[(o * 64 + c) * 2 + 1];
      }
      const float w = (half == 0) ? (part == 0 ? ws_ : -wr_)
                                  : (part == 0 ? wr_ : ws_);
      wAv[idx] = f2bf(w);
    }
  }
  if (idx < 32768) {
    { const int mt = (idx >> 9) & 15, cc = idx >> 13;
      wA1[idx] = f2bf(w1[(mt * 16 + lr) * 128 + cc * 32 + h * 8 + j]); }
    { const int mt = (idx >> 9) & 7, cc = idx >> 12;
      wA2[idx] = f2bf(w2[(mt * 16 + lr) * 256 + cc * 32 + h * 8 + j]); }
  }
  if (idx < 8192) {
    const int mt = (idx >> 9) & 3, cc = idx >> 11;
    wAg[idx] = f2bf(svw[(mt * 16 + lr) * 128 + cc * 32 + h * 8 + j]);
  }
}

// ---------------------------------------------------------------------------
// Convert x_s / x_v to bf16 granule layout [b][cg16][px][8units], 16B granules.
// xs: unit = channel. xv: unit = 2c+(0=u,1=v), interleaved.
// ---------------------------------------------------------------------------
__global__ __launch_bounds__(256) void k_cvt(
    const float* __restrict__ xs, const float* __restrict__ xv,
    uint4* __restrict__ xs8, uint4* __restrict__ xv8)
{
  const int NT = 2 * 16 * HW;
  const int stride = gridDim.x * 256;
  const int i0 = blockIdx.x * 256 + threadIdx.x;
  for (int idx = i0; idx < NT; idx += stride) {
    const int px = idx % HW;
    const int rest = idx / HW;
    const int cg = rest & 15, b = rest >> 4;
    const float* p = xs + ((size_t)(b * 128 + cg * 8)) * HW + px;
    uint32_t w0 = (uint32_t)f2bf(p[0]) | ((uint32_t)f2bf(p[(size_t)HW]) << 16);
    uint32_t w1 = (uint32_t)f2bf(p[(size_t)2*HW]) | ((uint32_t)f2bf(p[(size_t)3*HW]) << 16);
    uint32_t w2 = (uint32_t)f2bf(p[(size_t)4*HW]) | ((uint32_t)f2bf(p[(size_t)5*HW]) << 16);
    uint32_t w3 = (uint32_t)f2bf(p[(size_t)6*HW]) | ((uint32_t)f2bf(p[(size_t)7*HW]) << 16);
    xs8[idx] = make_uint4(w0, w1, w2, w3);
  }
  for (int idx = i0; idx < NT; idx += stride) {
    const int px = idx % HW;
    const int rest = idx / HW;
    const int ug = rest & 15, b = rest >> 4;
    const float* p = xv + (((size_t)(b * 64 + ug * 4)) * HW + px) * 2;
    const float2 q0 = *(const float2*)(p);
    const float2 q1 = *(const float2*)(p + (size_t)2 * HW);
    const float2 q2 = *(const float2*)(p + (size_t)4 * HW);
    const float2 q3 = *(const float2*)(p + (size_t)6 * HW);
    uint32_t w0 = (uint32_t)f2bf(q0.x) | ((uint32_t)f2bf(q0.y) << 16);
    uint32_t w1 = (uint32_t)f2bf(q1.x) | ((uint32_t)f2bf(q1.y) << 16);
    uint32_t w2 = (uint32_t)f2bf(q2.x) | ((uint32_t)f2bf(q2.y) << 16);
    uint32_t w3 = (uint32_t)f2bf(q3.x) | ((uint32_t)f2bf(q3.y) << 16);
    xv8[idx] = make_uint4(w0, w1, w2, w3);
  }
}

// ---------------------------------------------------------------------------
// Scalar conv via MFMA, async-staged. Tile 4x32 px, 128 oc, K=9*128.
// LDS: 204 pos x 16 granules, slot = ug ^ (pos&15) (swizzle via global src).
// ---------------------------------------------------------------------------
__global__ __launch_bounds__(256) void k_conv_s(
    const char* __restrict__ xs8, const ushort* __restrict__ wAs,
    const float* __restrict__ bias, ushort* __restrict__ sact8)
{
  __shared__ __align__(16) char ldsb[53248];   // 3328 granules
  const int t = threadIdx.x;
  const int bid = blockIdx.x;
  const int b  = bid / 540;
  const int r2 = bid % 540;
  const int rt = r2 / 12, ct = r2 % 12;
  const int y0 = rt * 4;
  int x0 = ct * 32; if (x0 > 328) x0 = 328;
  const char* xb = xs8 + (size_t)b * 16 * HW * 16;

  char* dst = ldsb + (t & 192) * 16;   // wave-uniform LDS base
  #pragma unroll
  for (int it = 0; it < 13; ++it) {
    int g = it * 256 + t; if (g > 3263) g = 3263;
    const int pos = g >> 4, sg = g & 15;
    const int ug = sg ^ (pos & 15);
    const int ir = pos / 34, ic = pos - ir * 34;
    int gy = y0 - 1 + ir; gy = max(0, min(179, gy));
    int gx = x0 - 1 + ic;
    if (gx < 0) gx += 360; else if (gx >= 360) gx -= 360;
    gload16(xb + (((size_t)ug * HW + gy * 360 + gx) << 4), dst + it * 4096);
  }
  __syncthreads();
  if (y0 == 0)
    for (int g2 = t; g2 < 544; g2 += 256) *(f32x4*)(ldsb + g2 * 16) = f32x4{0.f,0.f,0.f,0.f};
  if (y0 == 176)
    for (int g2 = t; g2 < 544; g2 += 256) *(f32x4*)(ldsb + (2720 + g2) * 16) = f32x4{0.f,0.f,0.f,0.f};
  __syncthreads();

  const int w = t >> 6, lane = t & 63;
  const int wm = w >> 1, wn = w & 1;
  const int lr = lane & 15, h = lane >> 4;

  f32x4 acc[4][4];
  #pragma unroll
  for (int i = 0; i < 4; ++i)
    #pragma unroll
    for (int n = 0; n < 4; ++n) acc[i][n] = f32x4{0.f,0.f,0.f,0.f};

  for (int tap = 0; tap < 9; ++tap) {
    const int dy = tap / 3, dx = tap - dy * 3;
    int rp[4];
    #pragma unroll
    for (int in = 0; in < 4; ++in) {
      const int nt = wn * 4 + in;
      rp[in] = ((nt >> 1) + dy) * 34 + (nt & 1) * 16 + lr + dx;
    }
    #pragma unroll
    for (int cc = 0; cc < 4; ++cc) {
      bf16x8 af[4];
      const ushort* ap = wAs + (size_t)(((tap * 4 + cc) * 8 + wm * 4) * 64 + lane) * 8;
      #pragma unroll
      for (int im = 0; im < 4; ++im) af[im] = *(const bf16x8*)(ap + im * 512);
      const int s0 = cc * 4 + h;
      #pragma unroll
      for (int in = 0; in < 4; ++in) {
        const bf16x8 bfr = *(const bf16x8*)(ldsb + rp[in] * 256 + ((s0 ^ (rp[in] & 15)) << 4));
        #pragma unroll
        for (int im = 0; im < 4; ++im) acc[im][in] = MFMA(af[im], bfr, acc[im][in]);
      }
    }
  }

  #pragma unroll
  for (int im = 0; im < 4; ++im) {
    #pragma unroll
    for (int r = 0; r < 4; ++r) {
      const int o = (wm * 4 + im) * 16 + h * 4 + r;
      const float bo = bias[o];
      ushort* op = sact8 + ((size_t)(b * 16 + (o >> 3)) * HW) * 8 + (o & 7);
      #pragma unroll
      for (int in = 0; in < 4; ++in) {
        const int nt = wn * 4 + in;
        const int gy = y0 + (nt >> 1);
        const int gx = x0 + (nt & 1) * 16 + lr;
        op[(size_t)(gy * 360 + gx) * 8] = f2bf(gelu_tanh(acc[im][in][r] + bo));
      }
    }
  }
}

// ---------------------------------------------------------------------------
// Vector (complex) conv via MFMA, async-staged; gate (bf16) + residual from LDS.
// ---------------------------------------------------------------------------
__global__ __launch_bounds__(256) void k_conv_v(
    const char* __restrict__ xv8, const ushort* __restrict__ wAv,
    const ushort* __restrict__ gateb, float* __restrict__ outv)
{
  __shared__ __align__(16) char ldsb[53248];
  const int t = threadIdx.x;
  const int bid = blockIdx.x;
  const int b  = bid / 540;
  const int r2 = bid % 540;
  const int rt = r2 / 12, ct = r2 % 12;
  const int y0 = rt * 4;
  int x0 = ct * 32; if (x0 > 328) x0 = 328;
  const char* xb = xv8 + (size_t)b * 16 * HW * 16;

  char* dst = ldsb + (t & 192) * 16;
  #pragma unroll
  for (int it = 0; it < 13; ++it) {
    int g = it * 256 + t; if (g > 3263) g = 3263;
    const int pos = g >> 4, sg = g & 15;
    const int ug = sg ^ (pos & 15);
    const int ir = pos / 34, ic = pos - ir * 34;
    int gy = y0 - 1 + ir; gy = max(0, min(179, gy));
    int gx = x0 - 1 + ic;
    if (gx < 0) gx += 360; else if (gx >= 360) gx -= 360;
    gload16(xb + (((size_t)ug * HW + gy * 360 + gx) << 4), dst + it * 4096);
  }
  __syncthreads();
  if (y0 == 0)
    for (int g2 = t; g2 < 544; g2 += 256) *(f32x4*)(ldsb + g2 * 16) = f32x4{0.f,0.f,0.f,0.f};
  if (y0 == 176)
    for (int g2 = t; g2 < 544; g2 += 256) *(f32x4*)(ldsb + (2720 + g2) * 16) = f32x4{0.f,0.f,0.f,0.f};
  __syncthreads();

  const int w = t >> 6, lane = t & 63;
  const int wm = w >> 1, wn = w & 1;
  const int lr = lane & 15, h = lane >> 4;
  int mtab[4];
  #pragma unroll
  for (int im = 0; im < 4; ++im) mtab[im] = wm * 2 + (im & 1) + (im >> 1) * 4;

  f32x4 acc[4][4];
  #pragma unroll
  for (int i = 0; i < 4; ++i)
    #pragma unroll
    for (int n = 0; n < 4; ++n) acc[i][n] = f32x4{0.f,0.f,0.f,0.f};

  for (int tap = 0; tap < 9; ++tap) {
    const int dy = tap / 3, dx = tap - dy * 3;
    int rp[4];
    #pragma unroll
    for (int in = 0; in < 4; ++in) {
      const int nt = wn * 4 + in;
      rp[in] = ((nt >> 1) + dy) * 34 + (nt & 1) * 16 + lr + dx;
    }
    #pragma unroll
    for (int cc = 0; cc < 4; ++cc) {
      bf16x8 af[4];
      #pragma unroll
      for (int im = 0; im < 4; ++im)
        af[im] = *(const bf16x8*)(wAv + (size_t)(((tap * 4 + cc) * 8 + mtab[im]) * 64 + lane) * 8);
      const int s0 = cc * 4 + h;
      #pragma unroll
      for (int in = 0; in < 4; ++in) {
        const bf16x8 bfr = *(const bf16x8*)(ldsb + rp[in] * 256 + ((s0 ^ (rp[in] & 15)) << 4));
        #pragma unroll
        for (int im = 0; im < 4; ++im) acc[im][in] = MFMA(af[im], bfr, acc[im][in]);
      }
    }
  }

  #pragma unroll
  for (int i = 0; i < 2; ++i) {
    #pragma unroll
    for (int r = 0; r < 4; ++r) {
      const int o = (wm * 2 + i) * 16 + h * 4 + r;
      const int sl = o >> 2;                 // (2o)>>3
      const int bo2 = ((2 * o) & 7) * 2;     // byte offset of (u,v) pair in granule
      #pragma unroll
      for (int in = 0; in < 4; ++in) {
        const int nt = wn * 4 + in;
        const int gy = y0 + (nt >> 1);
        const int gxl = (nt & 1) * 16 + lr;
        const int posc = ((nt >> 1) + 1) * 34 + 1 + gxl;
        const uint32_t uv = *(const uint32_t*)(ldsb + posc * 256 + ((sl ^ (posc & 15)) << 4) + bo2);
        const size_t pix = (size_t)(b * 64 + o) * HW + gy * 360 + x0 + gxl;
        const float g1 = 1.0f + bf2f(gateb[pix]);
        float2 rr;
        rr.x = acc[i][in][r]     + bf2f((ushort)(uv & 0xffffu)) * g1;
        rr.y = acc[i + 2][in][r] + bf2f((ushort)(uv >> 16)) * g1;
        *(float2*)(outv + pix * 2) = rr;
      }
    }
  }
}

// ---------------------------------------------------------------------------
// Fused MLP + gate + residual + LayerNorm via MFMA. 48-px strips (37 KB LDS).
// ---------------------------------------------------------------------------
__global__ __launch_bounds__(256) void k_mlp(
    const char* __restrict__ sact8, const float* __restrict__ x,
    const ushort* __restrict__ wA1, const float* __restrict__ b1,
    const ushort* __restrict__ wA2, const float* __restrict__ b2,
    const ushort* __restrict__ wAg, const float* __restrict__ svb,
    const float* __restrict__ gam, const float* __restrict__ bet,
    float* __restrict__ outs, ushort* __restrict__ gateb)
{
  __shared__ __align__(16) char ldsb[37248];
  char* sab = ldsb;                     // [48][256B]
  char* hbb = ldsb + 12288;             // [48][512B]
  float* mrs = (float*)(ldsb + 36864);  // [48][2]

  const int t = threadIdx.x;
  const int bid = blockIdx.x;
  const int b = bid / 1350, pb = bid % 1350;
  const int p0 = pb * 48;
  const int w = t >> 6, lane = t & 63, lr = lane & 15, h = lane >> 4;
  const int h16 = h << 4, lr16 = lr << 4;

  // stage sa via async DMA (48*16 = 768 granules)
  {
    char* dstm = sab + (t & 192) * 16;
    #pragma unroll
    for (int it = 0; it < 3; ++it) {
      const int g = it * 256 + t;
      const int px = g >> 4, sg = g & 15;
      const int ug = sg ^ (px & 15);
      gload16(sact8 + ((size_t)(b * 16 + ug) * HW + p0 + px) * 16, dstm + it * 4096);
    }
  }
  __syncthreads();

  // stage 1: h = gelu(W1 sa + b1); wave w -> h-channels [w*64, w*64+64)
  {
    f32x4 a1[4][3];
    #pragma unroll
    for (int i = 0; i < 4; ++i)
      #pragma unroll
      for (int n = 0; n < 3; ++n) a1[i][n] = f32x4{0.f,0.f,0.f,0.f};
    #pragma unroll
    for (int cc = 0; cc < 4; ++cc) {
      bf16x8 af[4];
      const ushort* ap = wA1 + (size_t)((cc * 16 + w * 4) * 64 + lane) * 8;
      #pragma unroll
      for (int im = 0; im < 4; ++im) af[im] = *(const bf16x8*)(ap + im * 512);
      const int gh = (cc << 6) + h16;
      #pragma unroll
      for (int in = 0; in < 3; ++in) {
        const bf16x8 bfr = *(const bf16x8*)(sab + ((in * 16 + lr) << 8) + (gh ^ lr16));
        #pragma unroll
        for (int im = 0; im < 4; ++im) a1[im][in] = MFMA(af[im], bfr, a1[im][in]);
      }
    }
    #pragma unroll
    for (int im = 0; im < 4; ++im) {
      const int C0 = (w * 4 + im) * 16 + h * 4;
      #pragma unroll
      for (int in = 0; in < 3; ++in) {
        const int px = in * 16 + lr;
        const float g0 = gelu_tanh(a1[im][in][0] + b1[C0 + 0]);
        const float g1 = gelu_tanh(a1[im][in][1] + b1[C0 + 1]);
        const float g2 = gelu_tanh(a1[im][in][2] + b1[C0 + 2]);
        const float g3 = gelu_tanh(a1[im][in][3] + b1[C0 + 3]);
        const int ad = (px << 9) + ((((C0 >> 3) ^ (px & 15))) << 4) + ((C0 & 7) << 1);
        *(uint32_t*)(hbb + ad)     = (uint32_t)f2bf(g0) | ((uint32_t)f2bf(g1) << 16);
        *(uint32_t*)(hbb + ad + 4) = (uint32_t)f2bf(g2) | ((uint32_t)f2bf(g3) << 16);
      }
    }
  }
  __syncthreads();

  // stage 2: s2 = sa + W2 h + b2 ; wave w -> channels [w*32, w*32+32)
  f32x4 a2[2][3];
  #pragma unroll
  for (int i = 0; i < 2; ++i)
    #pragma unroll
    for (int n = 0; n < 3; ++n) a2[i][n] = f32x4{0.f,0.f,0.f,0.f};
  #pragma unroll
  for (int cc = 0; cc < 8; ++cc) {
    const ushort* ap = wA2 + (size_t)((cc * 8 + w * 2) * 64 + lane) * 8;
    const bf16x8 af0 = *(const bf16x8*)(ap);
    const bf16x8 af1 = *(const bf16x8*)(ap + 512);
    const int gh = (cc << 6) + h16;
    #pragma unroll
    for (int in = 0; in < 3; ++in) {
      const bf16x8 bfr = *(const bf16x8*)(hbb + ((in * 16 + lr) << 9) + (gh ^ lr16));
      a2[0][in] = MFMA(af0, bfr, a2[0][in]);
      a2[1][in] = MFMA(af1, bfr, a2[1][in]);
    }
  }
  #pragma unroll
  for (int im = 0; im < 2; ++im) {
    const int C0 = (w * 2 + im) * 16 + h * 4;
    #pragma unroll
    for (int r = 0; r < 4; ++r) {
      const int c = C0 + r;
      const float bb = b2[c];
      #pragma unroll
      for (int in = 0; in < 3; ++in) {
        const int px = in * 16 + lr;
        const int ad = (px << 8) + ((((c >> 3) ^ (px & 15))) << 4) + ((c & 7) << 1);
        a2[im][in][r] += bb + bf2f(*(const ushort*)(sab + ad));
      }
    }
  }
  __syncthreads();   // all sa/hb reads done

  #pragma unroll
  for (int im = 0; im < 2; ++im) {
    const int C0 = (w * 2 + im) * 16 + h * 4;
    const int gsf = (w * 2 + im) * 4 + h;
    #pragma unroll
    for (int in = 0; in < 3; ++in) {
      const int px = in * 16 + lr;
      const int ad = (px << 8) + ((((C0 >> 3) ^ (px & 15))) << 4) + ((C0 & 7) << 1);
      *(uint32_t*)(sab + ad)     = (uint32_t)f2bf(a2[im][in][0]) | ((uint32_t)f2bf(a2[im][in][1]) << 16);
      *(uint32_t*)(sab + ad + 4) = (uint32_t)f2bf(a2[im][in][2]) | ((uint32_t)f2bf(a2[im][in][3]) << 16);
      const int ad2 = (px << 9) + ((gsf ^ (px & 15)) << 4);
      *(f32x4*)(hbb + ad2) = a2[im][in];
    }
  }
  __syncthreads();

  // s_final = s2 + x  (into fp32 buffer)
  for (int i = t; i < 128 * 48; i += 256) {
    const int c = i / 48, px = i - c * 48;
    const float xv_ = x[(size_t)(b * 128 + c) * HW + p0 + px];
    const int ad = (px << 9) + ((((c >> 2) ^ (px & 15))) << 4) + ((c & 3) << 2);
    *(float*)(hbb + ad) += xv_;
  }
  __syncthreads();

  // gate = svw * s2 + svb (bf16 out); wave w -> gate channels [w*16, w*16+16)
  {
    f32x4 ag[3];
    #pragma unroll
    for (int n = 0; n < 3; ++n) ag[n] = f32x4{0.f,0.f,0.f,0.f};
    #pragma unroll
    for (int cc = 0; cc < 4; ++cc) {
      const bf16x8 af = *(const bf16x8*)(wAg + (size_t)((cc * 4 + w) * 64 + lane) * 8);
      const int gh = (cc << 6) + h16;
      #pragma unroll
      for (int in = 0; in < 3; ++in) {
        const bf16x8 bfr = *(const bf16x8*)(sab + ((in * 16 + lr) << 8) + (gh ^ lr16));
        ag[in] = MFMA(af, bfr, ag[in]);
      }
    }
    #pragma unroll
    for (int r = 0; r < 4; ++r) {
      const int o = w * 16 + h * 4 + r;
      const float bb = svb[o];
      #pragma unroll
      for (int in = 0; in < 3; ++in)
        gateb[(size_t)(b * 64 + o) * HW + p0 + in * 16 + lr] = f2bf(ag[in][r] + bb);
    }
  }

  // LN stats
  if (t < 96) {
    const int px = t >> 1, half = t & 1;
    float sum = 0.f, sq = 0.f;
    #pragma unroll
    for (int i = 0; i < 16; ++i) {
      const int g = half * 16 + i;
      const f32x4 v = *(const f32x4*)(hbb + (px << 9) + ((g ^ (px & 15)) << 4));
      sum += v[0] + v[1] + v[2] + v[3];
      sq = fmaf(v[0], v[0], sq); sq = fmaf(v[1], v[1], sq);
      sq = fmaf(v[2], v[2], sq); sq = fmaf(v[3], v[3], sq);
    }
    sum += __shfl_xor(sum, 1);
    sq  += __shfl_xor(sq, 1);
    if (half == 0) {
      const float mean = sum * (1.0f / 128.0f);
      const float var  = sq * (1.0f / 128.0f) - mean * mean;
      mrs[px * 2 + 0] = mean;
      mrs[px * 2 + 1] = rsqrtf(var + 1e-6f);
    }
  }
  __syncthreads();

  for (int i = t; i < 128 * 48; i += 256) {
    const int c = i / 48, px = i - c * 48;
    const int ad = (px << 9) + ((((c >> 2) ^ (px & 15))) << 4) + ((c & 3) << 2);
    const float v = *(const float*)(hbb + ad);
    outs[(size_t)(b * 128 + c) * HW + p0 + px] =
        (v - mrs[px * 2]) * mrs[px * 2 + 1] * gam[c] + bet[c];
  }
}

// ---------------------------------------------------------------------------
extern "C" void kernel_launch(void* const* d_in, const int* in_sizes, int n_in,
                              void* d_out, int out_size, void* d_ws, size_t ws_size,
                              hipStream_t stream) {
  const float* x_s  = (const float*)d_in[0];
  const float* x_v  = (const float*)d_in[1];
  const float* cws  = (const float*)d_in[2];
  const float* cbs  = (const float*)d_in[3];
  const float* cwv  = (const float*)d_in[4];
  const float* pwss = (const float*)d_in[5];
  const float* pvt  = (const float*)d_in[6];
  const float* w1   = (const float*)d_in[7];
  const float* b1   = (const float*)d_in[8];
  const float* w2   = (const float*)d_in[9];
  const float* b2   = (const float*)d_in[10];
  const float* svw  = (const float*)d_in[11];
  const float* svb  = (const float*)d_in[12];
  const float* gam  = (const float*)d_in[13];
  const float* bet  = (const float*)d_in[14];

  char* wsb = (char*)d_ws;
  ushort* wAs  = (ushort*)(wsb);              // 294912 B
  ushort* wAv  = (ushort*)(wsb + 294912);     // 294912 B
  ushort* wA1  = (ushort*)(wsb + 589824);     // 65536 B
  ushort* wA2  = (ushort*)(wsb + 655360);     // 65536 B
  ushort* wAg  = (ushort*)(wsb + 720896);     // 16384 B
  char*   xs8  = wsb + 737280;                // 33177600 B
  char*   xv8  = wsb + 33914880;              // 33177600 B
  char*   sa8  = wsb + 67092480;              // 33177600 B (end 100270080)
  ushort* gateb = (ushort*)(wsb + 737280);    // aliases xs8 (dead after k_conv_s)

  float* outs = (float*)d_out;
  float* outv = outs + 16588800;

  k_fuse_w<<<576, 256, 0, stream>>>(cws, pwss, cwv, pvt, w1, w2, svw,
                                    wAs, wAv, wA1, wA2, wAg);
  k_cvt<<<2048, 256, 0, stream>>>(x_s, x_v, (uint4*)xs8, (uint4*)xv8);
  k_conv_s<<<1080, 256, 0, stream>>>(xs8, wAs, cbs, (ushort*)sa8);
  k_mlp<<<2700, 256, 0, stream>>>(sa8, x_s, wA1, b1, wA2, b2, wAg, svb,
                                  gam, bet, outs, gateb);
  k_conv_v<<<1080, 256, 0, stream>>>(xv8, wAv, gateb, outv);
}